// Round 15
// baseline (3090.851 us; speedup 1.0000x reference)
//
#include <hip/hip_runtime.h>
#include <math.h>

#ifndef M_PI
#define M_PI 3.14159265358979323846
#endif

#define BD 256
#define NB 16
#define DIM 1024
#define SMAX 288
#define NSTEPS 32
#define NPROPS 512
#define NTOK (16 * 256 * 1024)

__device__ __forceinline__ double wred_sum(double v) {
#pragma unroll
    for (int o = 32; o > 0; o >>= 1) v += __shfl_down(v, o, 64);
    return v;
}
__device__ __forceinline__ double wred_max(double v) {
#pragma unroll
    for (int o = 32; o > 0; o >>= 1) { double w = __shfl_down(v, o, 64); if (w > v) v = w; }
    return v;
}
// 256-thread (4-wave) variants
__device__ double block_sum(double v, double* sc) {
    v = wred_sum(v);
    int tid = threadIdx.x;
    if ((tid & 63) == 0) sc[tid >> 6] = v;
    __syncthreads();
    double r = sc[0] + sc[1] + sc[2] + sc[3];
    __syncthreads();
    return r;
}
__device__ double block_max(double v, double* sc) {
    v = wred_max(v);
    int tid = threadIdx.x;
    if ((tid & 63) == 0) sc[tid >> 6] = v;
    __syncthreads();
    double r = fmax(fmax(sc[0], sc[1]), fmax(sc[2], sc[3]));
    __syncthreads();
    return r;
}
// 1024-thread (16-wave) variant
__device__ double block_sum16(double v, double* sc) {
    v = wred_sum(v);
    int tid = threadIdx.x;
    if ((tid & 63) == 0) sc[tid >> 6] = v;
    __syncthreads();
    double r = 0;
#pragma unroll
    for (int i = 0; i < 16; ++i) r += sc[i];
    __syncthreads();
    return r;
}

// ---- FUSED: canonicalize tokens (int32 OR int64) + per-token LN stats ----
__global__ __launch_bounds__(256) void k_tok_stats(const int* __restrict__ tok32,
                                                   signed char* __restrict__ tokc,
                                                   double* __restrict__ mu, double* __restrict__ rs) {
    __shared__ int flag;
    __shared__ double sc[4];
    int T = blockIdx.x, tid = threadIdx.x;
    if (tid == 0) {
        int nz = 0;
        for (int i = 1; i < 512; i += 2) nz |= tok32[i];
        flag = nz;
    }
    __syncthreads();
    bool is64 = (flag == 0);
    signed char* row = tokc + (size_t)T * DIM;
    double s = 0;
#pragma unroll
    for (int it = 0; it < 4; ++it) {
        size_t idx = (size_t)T * 1024 + it * BD + tid;
        int v = is64 ? tok32[2 * idx] : tok32[idx];
        row[it * BD + tid] = (signed char)v;
        s += (double)v;
    }
    s = block_sum(s, sc);
    double m = s * (1.0 / 1024.0);
    double ss = 0;
    __syncthreads();
    for (int i = tid; i < DIM; i += BD) { double d = (double)row[i] - m; ss += d * d; }
    ss = block_sum(ss, sc);
    if (tid == 0) { mu[T] = m; rs[T] = 1.0 / sqrt(ss * (1.0 / 1024.0) + 1e-5); }
}

// ---- init: xl (fp32; holds only 0/1 -> exact) = last token row; LN stats ----
__global__ __launch_bounds__(256) void k_init(const signed char* __restrict__ tokc,
                                              const double* __restrict__ mu, const double* __restrict__ rs,
                                              float* __restrict__ xl,
                                              double* __restrict__ mub, double* __restrict__ rsb) {
    int b = blockIdx.x, tid = threadIdx.x;
    int T = b * 256 + 255;
    if (tid == 0) { mub[b] = mu[T]; rsb[b] = rs[T]; }
    for (int i = tid; i < DIM; i += BD)
        xl[b * DIM + i] = (float)tokc[(size_t)T * DIM + i];
}

// ---- prefix K,V GEMM in fp32 -> fp32 KV cache (64-row T-tiles) ----
__global__ __launch_bounds__(256) void k_prefix(const signed char* __restrict__ tokc,
        const double* __restrict__ mu, const double* __restrict__ rs,
        const float* __restrict__ Wqkv, const float* __restrict__ bqkv,
        const float* __restrict__ g1, const float* __restrict__ b1,
        float* __restrict__ Kcf, float* __restrict__ Vcf) {
    __shared__ float Hs[64 * 65];
    __shared__ float Ws[64 * 64];
    int tid = threadIdx.x;
    int tx = tid & 63, ty = tid >> 6;
    int j0 = blockIdx.x * 64;
    int T0 = blockIdx.y * 64;
    float acc[16];
#pragma unroll
    for (int a = 0; a < 16; ++a) acc[a] = 0.f;
    for (int kc = 0; kc < DIM; kc += 64) {
#pragma unroll
        for (int it = 0; it < 4; ++it) {
            int e = tid * 4 + it * 1024;
            int k4 = e & 63, t = e >> 6;
            int T = T0 + t;
            char4  xc = *(const char4*)&tokc[(size_t)T * DIM + kc + k4];
            float4 gv = *(const float4*)&g1[kc + k4];
            float4 bv = *(const float4*)&b1[kc + k4];
            double muT = mu[T], rsT = rs[T];
            Hs[(k4 + 0) * 65 + t] = (float)(((double)xc.x - muT) * rsT * (double)gv.x + (double)bv.x);
            Hs[(k4 + 1) * 65 + t] = (float)(((double)xc.y - muT) * rsT * (double)gv.y + (double)bv.y);
            Hs[(k4 + 2) * 65 + t] = (float)(((double)xc.z - muT) * rsT * (double)gv.z + (double)bv.z);
            Hs[(k4 + 3) * 65 + t] = (float)(((double)xc.w - muT) * rsT * (double)gv.w + (double)bv.w);
        }
#pragma unroll
        for (int it = 0; it < 4; ++it) {
            int e = tid * 4 + it * 1024;
            int k = e >> 6, j = e & 63;
            float4 wv = *(const float4*)&Wqkv[(size_t)(kc + k) * 3072 + 1024 + j0 + j];
            *(float4*)&Ws[k * 64 + j] = wv;
        }
        __syncthreads();
#pragma unroll 4
        for (int k = 0; k < 64; ++k) {
            float w = Ws[k * 64 + tx];
#pragma unroll
            for (int a = 0; a < 16; ++a)
                acc[a] += Hs[k * 65 + ty * 16 + a] * w;
        }
        __syncthreads();
    }
    int colg = j0 + tx;
    float bias = bqkv[1024 + colg];
    bool isK = (colg < 1024);
#pragma unroll
    for (int a = 0; a < 16; ++a) {
        int T = T0 + ty * 16 + a;
        int b = T >> 8, pos = T & 255;
        float v = acc[a] + bias;
        if (isK) Kcf[((size_t)b * SMAX + pos) * DIM + colg] = v;
        else     Vcf[((size_t)b * SMAX + pos) * DIM + colg - 1024] = v;
    }
}

// ---- QKV GEMV with analytic-LN staging; float4 staging loads ----
__global__ __launch_bounds__(256) void k_qkv(const float* __restrict__ xl,
        const double* __restrict__ mub, const double* __restrict__ rsb,
        const float* __restrict__ g1, const float* __restrict__ b1,
        const float* __restrict__ Wqkv, float* __restrict__ P1) {
    __shared__ double As[16 * 64];
    __shared__ float  Ws[64 * 64];
    int tid = threadIdx.x, tx = tid & 63, ty = tid >> 6;
    int j0 = blockIdx.x * 64;
    int k0 = blockIdx.y * 128;
    double acc[4] = {0, 0, 0, 0};
    for (int kc = 0; kc < 128; kc += 64) {
        {
            int bq = tid >> 4, kq = (tid & 15) * 4;
            int kk = k0 + kc + kq;
            float4 xv = *(const float4*)&xl[(size_t)bq * DIM + kk];
            float4 gv = *(const float4*)&g1[kk];
            float4 bv = *(const float4*)&b1[kk];
            double mb = mub[bq], rb = rsb[bq];
            double* d = &As[bq * 64 + kq];
            d[0] = ((double)xv.x - mb) * rb * (double)gv.x + (double)bv.x;
            d[1] = ((double)xv.y - mb) * rb * (double)gv.y + (double)bv.y;
            d[2] = ((double)xv.z - mb) * rb * (double)gv.z + (double)bv.z;
            d[3] = ((double)xv.w - mb) * rb * (double)gv.w + (double)bv.w;
        }
#pragma unroll
        for (int it = 0; it < 4; ++it) {
            int e = tid * 4 + it * 1024;
            int k = e >> 6, j = e & 63;
            float4 wv = *(const float4*)&Wqkv[(size_t)(k0 + kc + k) * 3072 + j0 + j];
            *(float4*)&Ws[k * 64 + j] = wv;
        }
        __syncthreads();
#pragma unroll 8
        for (int k = 0; k < 64; ++k) {
            double w = (double)Ws[k * 64 + tx];
            acc[0] += As[(ty * 4 + 0) * 64 + k] * w;
            acc[1] += As[(ty * 4 + 1) * 64 + k] * w;
            acc[2] += As[(ty * 4 + 2) * 64 + k] * w;
            acc[3] += As[(ty * 4 + 3) * 64 + k] * w;
        }
        __syncthreads();
    }
#pragma unroll
    for (int a = 0; a < 4; ++a)
        P1[((size_t)(blockIdx.y * 16 + ty * 4 + a)) * 3072 + j0 + tx] = (float)acc[a];
}

// ---- batched 16-row GEMV: fp32 A, fp32 partial out; float4 staging ----
__global__ __launch_bounds__(256) void mm16ff(const float* __restrict__ A, int K,
        const float* __restrict__ W, int ldw, float* __restrict__ P, int ncols) {
    __shared__ double As[16 * 64];
    __shared__ float  Ws[64 * 64];
    int tid = threadIdx.x, tx = tid & 63, ty = tid >> 6;
    int j0 = blockIdx.x * 64;
    int klen = K / gridDim.y;
    int k0 = blockIdx.y * klen;
    double acc[4] = {0, 0, 0, 0};
    for (int kc = 0; kc < klen; kc += 64) {
        {
            int bq = tid >> 4, kq = (tid & 15) * 4;
            float4 av = *(const float4*)&A[(size_t)bq * K + k0 + kc + kq];
            double* d = &As[bq * 64 + kq];
            d[0] = (double)av.x; d[1] = (double)av.y;
            d[2] = (double)av.z; d[3] = (double)av.w;
        }
#pragma unroll
        for (int it = 0; it < 4; ++it) {
            int e = tid * 4 + it * 1024;
            int k = e >> 6, j = e & 63;
            float4 wv = *(const float4*)&W[(size_t)(k0 + kc + k) * ldw + j0 + j];
            *(float4*)&Ws[k * 64 + j] = wv;
        }
        __syncthreads();
#pragma unroll 8
        for (int k = 0; k < 64; ++k) {
            double w = (double)Ws[k * 64 + tx];
            acc[0] += As[(ty * 4 + 0) * 64 + k] * w;
            acc[1] += As[(ty * 4 + 1) * 64 + k] * w;
            acc[2] += As[(ty * 4 + 2) * 64 + k] * w;
            acc[3] += As[(ty * 4 + 3) * 64 + k] * w;
        }
        __syncthreads();
    }
#pragma unroll
    for (int a = 0; a < 4; ++a)
        P[((size_t)(blockIdx.y * 16 + ty * 4 + a)) * ncols + j0 + tx] = (float)acc[a];
}

// ---- FUSED gelu+GEMV for mproj: A = gelu(sum8 P3 + bfc), W = Wmp[4096x1024].
// grid (16, 16), klen = 256. gelu in fp64, rounded to fp32 before staging ->
// matches the old k_gelu->m_(fp32)->mm16ff path bitwise. gelu recomputed per
// column-tile (16x) but grid/occupancy preserved (the r7 failure mode avoided).
__global__ __launch_bounds__(256) void mm16g(const float* __restrict__ P3,
        const float* __restrict__ bfc, const float* __restrict__ W,
        float* __restrict__ P) {
    __shared__ double As[16 * 64];
    __shared__ float  Ws[64 * 64];
    int tid = threadIdx.x, tx = tid & 63, ty = tid >> 6;
    int j0 = blockIdx.x * 64;
    int k0 = blockIdx.y * 256;
    const double c = sqrt(2.0 / M_PI);
    double acc[4] = {0, 0, 0, 0};
    for (int kc = 0; kc < 256; kc += 64) {
        {
            int bq = tid >> 4, kq = (tid & 15) * 4;
            int kk = k0 + kc + kq;
            float4 bv = *(const float4*)&bfc[kk];
            double u0 = bv.x, u1 = bv.y, u2 = bv.z, u3 = bv.w;
#pragma unroll
            for (int ks = 0; ks < 8; ++ks) {
                float4 pv = *(const float4*)&P3[((size_t)(ks * 16 + bq)) * 4096 + kk];
                u0 += (double)pv.x; u1 += (double)pv.y; u2 += (double)pv.z; u3 += (double)pv.w;
            }
            double* d = &As[bq * 64 + kq];
            d[0] = (double)(float)(0.5 * u0 * (1.0 + tanh(c * (u0 + 0.044715 * u0 * u0 * u0))));
            d[1] = (double)(float)(0.5 * u1 * (1.0 + tanh(c * (u1 + 0.044715 * u1 * u1 * u1))));
            d[2] = (double)(float)(0.5 * u2 * (1.0 + tanh(c * (u2 + 0.044715 * u2 * u2 * u2))));
            d[3] = (double)(float)(0.5 * u3 * (1.0 + tanh(c * (u3 + 0.044715 * u3 * u3 * u3))));
        }
#pragma unroll
        for (int it = 0; it < 4; ++it) {
            int e = tid * 4 + it * 1024;
            int k = e >> 6, j = e & 63;
            float4 wv = *(const float4*)&W[(size_t)(k0 + kc + k) * DIM + j0 + j];
            *(float4*)&Ws[k * 64 + j] = wv;
        }
        __syncthreads();
#pragma unroll 8
        for (int k = 0; k < 64; ++k) {
            double w = (double)Ws[k * 64 + tx];
            acc[0] += As[(ty * 4 + 0) * 64 + k] * w;
            acc[1] += As[(ty * 4 + 1) * 64 + k] * w;
            acc[2] += As[(ty * 4 + 2) * 64 + k] * w;
            acc[3] += As[(ty * 4 + 3) * 64 + k] * w;
        }
        __syncthreads();
    }
#pragma unroll
    for (int a = 0; a < 4; ++a)
        P[((size_t)(blockIdx.y * 16 + ty * 4 + a)) * DIM + j0 + tx] = (float)acc[a];
}

// ---- transposed-W variant: fp32 A, fp32 partial out; float4 staging ----
__global__ __launch_bounds__(256) void mm16_tf(const float* __restrict__ A, int K,
        const float* __restrict__ Wt, float* __restrict__ P, int ncols) {
    __shared__ double As[16 * 64];
    __shared__ float  Ws[64 * 65];
    int tid = threadIdx.x, tx = tid & 63, ty = tid >> 6;
    int j0 = blockIdx.x * 64;
    int klen = K / gridDim.y;
    int k0 = blockIdx.y * klen;
    double acc[4] = {0, 0, 0, 0};
    for (int kc = 0; kc < klen; kc += 64) {
        {
            int bq = tid >> 4, kq = (tid & 15) * 4;
            float4 av = *(const float4*)&A[(size_t)bq * K + k0 + kc + kq];
            double* d = &As[bq * 64 + kq];
            d[0] = (double)av.x; d[1] = (double)av.y;
            d[2] = (double)av.z; d[3] = (double)av.w;
        }
#pragma unroll
        for (int it = 0; it < 4; ++it) {
            int e = tid * 4 + it * 1024;
            int j = e >> 6, k = e & 63;
            float4 wv = *(const float4*)&Wt[(size_t)(j0 + j) * K + k0 + kc + k];
            Ws[(k + 0) * 65 + j] = wv.x;
            Ws[(k + 1) * 65 + j] = wv.y;
            Ws[(k + 2) * 65 + j] = wv.z;
            Ws[(k + 3) * 65 + j] = wv.w;
        }
        __syncthreads();
#pragma unroll 8
        for (int k = 0; k < 64; ++k) {
            double w = (double)Ws[k * 65 + tx];
            acc[0] += As[(ty * 4 + 0) * 64 + k] * w;
            acc[1] += As[(ty * 4 + 1) * 64 + k] * w;
            acc[2] += As[(ty * 4 + 2) * 64 + k] * w;
            acc[3] += As[(ty * 4 + 3) * 64 + k] * w;
        }
        __syncthreads();
    }
#pragma unroll
    for (int a = 0; a < 4; ++a)
        P[((size_t)(blockIdx.y * 16 + ty * 4 + a)) * ncols + j0 + tx] = (float)acc[a];
}

// ---- FUSED: combine(P1) + scores + fresh K/V append. grid (NB, 9) ----
__global__ __launch_bounds__(256) void k_scores(const float* __restrict__ P1,
        const float* __restrict__ bqkv, float* __restrict__ Kcf, float* __restrict__ Vcf,
        double* __restrict__ sco, int S) {
    __shared__ double qs[DIM];
    __shared__ float  ksf[DIM];
    int b = blockIdx.x, tid = threadIdx.x;
    int pos = S - 1;
    {
        int c4 = tid * 4;
        float4 bq4 = *(const float4*)&bqkv[c4];
        double s0 = bq4.x, s1 = bq4.y, s2 = bq4.z, s3 = bq4.w;
#pragma unroll
        for (int ks = 0; ks < 8; ++ks) {
            float4 pv = *(const float4*)&P1[((size_t)(ks * 16 + b)) * 3072 + c4];
            s0 += (double)pv.x; s1 += (double)pv.y; s2 += (double)pv.z; s3 += (double)pv.w;
        }
        qs[c4] = s0; qs[c4 + 1] = s1; qs[c4 + 2] = s2; qs[c4 + 3] = s3;
    }
    if ((int)blockIdx.y == (pos >> 5)) {
        int c4 = tid * 4;
        float4 bk4 = *(const float4*)&bqkv[1024 + c4];
        float4 bv4 = *(const float4*)&bqkv[2048 + c4];
        double k0s = bk4.x, k1s = bk4.y, k2s = bk4.z, k3s = bk4.w;
        double v0s = bv4.x, v1s = bv4.y, v2s = bv4.z, v3s = bv4.w;
#pragma unroll
        for (int ks = 0; ks < 8; ++ks) {
            const float* Pr = &P1[((size_t)(ks * 16 + b)) * 3072];
            float4 pk = *(const float4*)&Pr[1024 + c4];
            float4 pv = *(const float4*)&Pr[2048 + c4];
            k0s += (double)pk.x; k1s += (double)pk.y; k2s += (double)pk.z; k3s += (double)pk.w;
            v0s += (double)pv.x; v1s += (double)pv.y; v2s += (double)pv.z; v3s += (double)pv.w;
        }
        float4 kf4 = make_float4((float)k0s, (float)k1s, (float)k2s, (float)k3s);
        *(float4*)&ksf[c4] = kf4;
        *(float4*)&Kcf[((size_t)b * SMAX + pos) * DIM + c4] = kf4;
        *(float4*)&Vcf[((size_t)b * SMAX + pos) * DIM + c4] =
            make_float4((float)v0s, (float)v1s, (float)v2s, (float)v3s);
    }
    __syncthreads();
    int lane = tid & 63, w = tid >> 6;
    int base = blockIdx.y * 32 + w * 8;
    for (int r = 0; r < 8; ++r) {
        int p = base + r;
        if (p >= S) break;
        double acc = 0;
        const float4* kp4 = (p == pos) ? (const float4*)ksf
                                       : (const float4*)(Kcf + ((size_t)b * SMAX + p) * DIM);
#pragma unroll
        for (int ii = 0; ii < 4; ++ii) {
            float4 kv = kp4[lane + 64 * ii];
            int e = 4 * (lane + 64 * ii);
            acc += qs[e] * (double)kv.x + qs[e + 1] * (double)kv.y
                 + qs[e + 2] * (double)kv.z + qs[e + 3] * (double)kv.w;
        }
        acc = wred_sum(acc);
        if (lane == 0) sco[b * SMAX + p] = acc * 0.03125;  // /sqrt(1024)
    }
}

// ---- softmax (redundant/block) + partial PV over fp32 V -> AOp fp32 ----
__global__ __launch_bounds__(256) void k_attnp(const double* __restrict__ sco, const float* __restrict__ Vcf,
                                               float* __restrict__ AOp, int S) {
    __shared__ double ps[SMAX];
    __shared__ double sc[4];
    int b = blockIdx.x, sub = blockIdx.y, tid = threadIdx.x;
    int dch = sub & 3, sch = sub >> 2;
    double lm = -1e300;
    for (int i = tid; i < S; i += BD) { double v = sco[b * SMAX + i]; ps[i] = v; if (v > lm) lm = v; }
    __syncthreads();
    double mx = block_max(lm, sc);
    double le = 0;
    for (int i = tid; i < S; i += BD) { double e = exp(ps[i] - mx); ps[i] = e; le += e; }
    double den = block_sum(le, sc);
    int d = dch * 256 + tid;
    int p0 = sch * 36, p1 = p0 + 36; if (p1 > S) p1 = S;
    const float* Vb = Vcf + (size_t)b * SMAX * DIM + d;
    double a0 = 0, a1 = 0, a2 = 0, a3 = 0;
    int p = p0;
    for (; p + 4 <= p1; p += 4) {
        a0 += ps[p + 0] * (double)Vb[(size_t)(p + 0) * DIM];
        a1 += ps[p + 1] * (double)Vb[(size_t)(p + 1) * DIM];
        a2 += ps[p + 2] * (double)Vb[(size_t)(p + 2) * DIM];
        a3 += ps[p + 3] * (double)Vb[(size_t)(p + 3) * DIM];
    }
    for (; p < p1; ++p) a0 += ps[p] * (double)Vb[(size_t)p * DIM];
    AOp[((size_t)(sch * 16 + b)) * DIM + d] = (float)(((a0 + a1) + (a2 + a3)) / den);
}

// ---- attn-proj GEMV: float4-staged sum of 8 AOp partials, GEMV Wap -> P2 ----
__global__ __launch_bounds__(256) void k_aproj(const float* __restrict__ AOp,
        const float* __restrict__ Wap, float* __restrict__ P2) {
    __shared__ double As[16 * 64];
    __shared__ float  Ws[64 * 64];
    int tid = threadIdx.x, tx = tid & 63, ty = tid >> 6;
    int j0 = blockIdx.x * 64;
    int k0 = blockIdx.y * 128;
    double acc[4] = {0, 0, 0, 0};
    for (int kc = 0; kc < 128; kc += 64) {
        {
            int bq = tid >> 4, kq = (tid & 15) * 4;
            const float* col = AOp + (size_t)bq * DIM + k0 + kc + kq;
            double s0 = 0, s1 = 0, s2 = 0, s3 = 0;
#pragma unroll
            for (int sct = 0; sct < 8; ++sct) {
                float4 v = *(const float4*)&col[(size_t)sct * 16 * DIM];
                s0 += (double)v.x; s1 += (double)v.y; s2 += (double)v.z; s3 += (double)v.w;
            }
            double* d = &As[bq * 64 + kq];
            d[0] = s0; d[1] = s1; d[2] = s2; d[3] = s3;
        }
#pragma unroll
        for (int it = 0; it < 4; ++it) {
            int e = tid * 4 + it * 1024;
            int k = e >> 6, j = e & 63;
            float4 wv = *(const float4*)&Wap[(size_t)(k0 + kc + k) * DIM + j0 + j];
            *(float4*)&Ws[k * 64 + j] = wv;
        }
        __syncthreads();
#pragma unroll 8
        for (int k = 0; k < 64; ++k) {
            double w = (double)Ws[k * 64 + tx];
            acc[0] += As[(ty * 4 + 0) * 64 + k] * w;
            acc[1] += As[(ty * 4 + 1) * 64 + k] * w;
            acc[2] += As[(ty * 4 + 2) * 64 + k] * w;
            acc[3] += As[(ty * 4 + 3) * 64 + k] * w;
        }
        __syncthreads();
    }
#pragma unroll
    for (int a = 0; a < 4; ++a)
        P2[((size_t)(blockIdx.y * 16 + ty * 4 + a)) * DIM + j0 + tx] = (float)acc[a];
}

// ---- x2 = xl + aproj + bias; LN2 -> h2. 1024 threads, 1 elem/thread ----
__global__ __launch_bounds__(1024) void k_ln2(const float* __restrict__ xl, const float* __restrict__ P2,
        const float* __restrict__ bap, const float* __restrict__ g2, const float* __restrict__ b2,
        float* __restrict__ x2, float* __restrict__ h2) {
    __shared__ double sc[16];
    int b = blockIdx.x, i = threadIdx.x;
    double s0 = (double)xl[b * DIM + i] + (double)bap[i];
#pragma unroll
    for (int ks = 0; ks < 8; ++ks) s0 += (double)P2[((size_t)(ks * 16 + b)) * DIM + i];
    x2[b * DIM + i] = (float)s0;
    double s = block_sum16(s0, sc);
    double m = s * (1.0 / 1024.0);
    double d = s0 - m;
    double ss = block_sum16(d * d, sc);
    double r = 1.0 / sqrt(ss * (1.0 / 1024.0) + 1e-5);
    h2[b * DIM + i] = (float)(d * r * (double)g2[i] + (double)b2[i]);
}

// ---- x3 = x2 + mproj + bias; LNf -> hf. 1024 threads, 1 elem/thread ----
__global__ __launch_bounds__(1024) void k_lnf(const float* __restrict__ x2, const float* __restrict__ P4,
        const float* __restrict__ bmp, const float* __restrict__ gf, const float* __restrict__ bf,
        float* __restrict__ hf) {
    __shared__ double sc[16];
    int b = blockIdx.x, i = threadIdx.x;
    double s0 = (double)x2[b * DIM + i] + (double)bmp[i];
#pragma unroll
    for (int ks = 0; ks < 16; ++ks) s0 += (double)P4[((size_t)(ks * 16 + b)) * DIM + i];
    double s = block_sum16(s0, sc);
    double m = s * (1.0 / 1024.0);
    double d = s0 - m;
    double ss = block_sum16(d * d, sc);
    double r = 1.0 / sqrt(ss * (1.0 / 1024.0) + 1e-5);
    hf[b * DIM + i] = (float)(d * r * (double)gf[i] + (double)bf[i]);
}

// ---- logits + threshold -> xl; analytic LN1 stats. 1024 threads ----
__global__ __launch_bounds__(1024) void k_final(const float* __restrict__ P5, float* __restrict__ out,
                                                float* __restrict__ xl,
                                                double* __restrict__ mub, double* __restrict__ rsb, int t) {
    __shared__ double sc[16];
    int b = blockIdx.x, tid = threadIdx.x;
    double cnt = 0;
    if (tid < NPROPS) {
        double lg = 0;
#pragma unroll
        for (int ks = 0; ks < 8; ++ks) lg += (double)P5[((size_t)(ks * 16 + b)) * NPROPS + tid];
        out[((size_t)b * NSTEPS + t) * NPROPS + tid] = (float)lg;
        float bit = (lg > 0.0) ? 1.0f : 0.0f;
        xl[b * DIM + tid] = 0.0f;
        xl[b * DIM + NPROPS + tid] = bit;
        cnt = (double)bit;
    }
    double s = block_sum16(cnt, sc);
    double mean = s * (1.0 / 1024.0);
    double var = mean - mean * mean;
    double r = 1.0 / sqrt(var + 1e-5);
    if (tid == 0) { mub[b] = mean; rsb[b] = r; }
}

extern "C" void kernel_launch(void* const* d_in, const int* in_sizes, int n_in,
                              void* d_out, int out_size, void* d_ws, size_t ws_size,
                              hipStream_t stream) {
    const int*   tok  = (const int*)d_in[0];
    const float* Wqkv = (const float*)d_in[1];
    const float* bqkv = (const float*)d_in[2];
    const float* Wap  = (const float*)d_in[3];
    const float* bap  = (const float*)d_in[4];
    const float* g1   = (const float*)d_in[5];
    const float* b1   = (const float*)d_in[6];
    const float* g2   = (const float*)d_in[7];
    const float* b2   = (const float*)d_in[8];
    const float* Wfc  = (const float*)d_in[9];
    const float* bfc  = (const float*)d_in[10];
    const float* Wmp  = (const float*)d_in[11];
    const float* bmp  = (const float*)d_in[12];
    const float* gf   = (const float*)d_in[13];
    const float* bf   = (const float*)d_in[14];
    const float* Wsc  = (const float*)d_in[15];
    float* out = (float*)d_out;

    char* w = (char*)d_ws;
    size_t off = 0;
    auto alloc = [&](size_t bytes) -> void* {
        void* p = (void*)(w + off);
        off += (bytes + 255) & ~(size_t)255;
        return p;
    };
    float*       Kcf  = (float*)alloc((size_t)NB * SMAX * DIM * 4);
    float*       Vcf  = (float*)alloc((size_t)NB * SMAX * DIM * 4);
    double*      mu   = (double*)alloc(4096 * 8);
    double*      rs   = (double*)alloc(4096 * 8);
    double*      mub  = (double*)alloc(NB * 8);
    double*      rsb  = (double*)alloc(NB * 8);
    float*       xl   = (float*)alloc((size_t)NB * DIM * 4);
    double*      sco  = (double*)alloc((size_t)NB * SMAX * 8);
    float*       AOp  = (float*)alloc((size_t)8 * NB * DIM * 4);
    float*       x2   = (float*)alloc((size_t)NB * DIM * 4);
    float*       h2   = (float*)alloc((size_t)NB * DIM * 4);
    float*       hf   = (float*)alloc((size_t)NB * DIM * 4);
    float*       P1   = (float*)alloc((size_t)8 * NB * 3072 * 4);
    float*       P2   = (float*)alloc((size_t)8 * NB * 1024 * 4);
    float*       P3   = (float*)alloc((size_t)8 * NB * 4096 * 4);
    float*       P4   = (float*)alloc((size_t)16 * NB * 1024 * 4);
    float*       P5   = (float*)alloc((size_t)8 * NB * 512 * 4);
    signed char* tokc = (signed char*)alloc((size_t)NTOK);
    if (off > ws_size) return;  // fail visibly (output stays poisoned)

    k_tok_stats<<<4096, BD, 0, stream>>>(tok, tokc, mu, rs);
    k_init<<<NB, BD, 0, stream>>>(tokc, mu, rs, xl, mub, rsb);
    k_prefix<<<dim3(32, 64), BD, 0, stream>>>(tokc, mu, rs, Wqkv, bqkv, g1, b1, Kcf, Vcf);

    for (int t = 0; t < NSTEPS; ++t) {
        int S = 256 + t;
        k_qkv<<<dim3(48, 8), BD, 0, stream>>>(xl, mub, rsb, g1, b1, Wqkv, P1);
        k_scores<<<dim3(NB, 9), BD, 0, stream>>>(P1, bqkv, Kcf, Vcf, sco, S);
        k_attnp<<<dim3(NB, 32), BD, 0, stream>>>(sco, Vcf, AOp, S);
        k_aproj<<<dim3(16, 8), BD, 0, stream>>>(AOp, Wap, P2);
        k_ln2<<<NB, 1024, 0, stream>>>(xl, P2, bap, g2, b2, x2, h2);
        mm16ff<<<dim3(64, 8), BD, 0, stream>>>(h2, 1024, Wfc, 4096, P3, 4096);
        mm16g<<<dim3(16, 16), BD, 0, stream>>>(P3, bfc, Wmp, P4);
        k_lnf<<<NB, 1024, 0, stream>>>(x2, P4, bmp, gf, bf, hf);
        mm16_tf<<<dim3(8, 8), BD, 0, stream>>>(hf, 1024, Wsc, P5, 512);
        k_final<<<NB, 1024, 0, stream>>>(P5, out, xl, mub, rsb, t);
    }
}

// Round 16
// 3004.791 us; speedup vs baseline: 1.0286x; 1.0286x over previous
//
#include <hip/hip_runtime.h>
#include <math.h>

#ifndef M_PI
#define M_PI 3.14159265358979323846
#endif

#define BD 256
#define NB 16
#define DIM 1024
#define SMAX 288
#define NSTEPS 32
#define NPROPS 512
#define NTOK (16 * 256 * 1024)

__device__ __forceinline__ double wred_sum(double v) {
#pragma unroll
    for (int o = 32; o > 0; o >>= 1) v += __shfl_down(v, o, 64);
    return v;
}
__device__ __forceinline__ double wred_max(double v) {
#pragma unroll
    for (int o = 32; o > 0; o >>= 1) { double w = __shfl_down(v, o, 64); if (w > v) v = w; }
    return v;
}
// 256-thread (4-wave) variants
__device__ double block_sum(double v, double* sc) {
    v = wred_sum(v);
    int tid = threadIdx.x;
    if ((tid & 63) == 0) sc[tid >> 6] = v;
    __syncthreads();
    double r = sc[0] + sc[1] + sc[2] + sc[3];
    __syncthreads();
    return r;
}
__device__ double block_max(double v, double* sc) {
    v = wred_max(v);
    int tid = threadIdx.x;
    if ((tid & 63) == 0) sc[tid >> 6] = v;
    __syncthreads();
    double r = fmax(fmax(sc[0], sc[1]), fmax(sc[2], sc[3]));
    __syncthreads();
    return r;
}
// 1024-thread (16-wave) variant
__device__ double block_sum16(double v, double* sc) {
    v = wred_sum(v);
    int tid = threadIdx.x;
    if ((tid & 63) == 0) sc[tid >> 6] = v;
    __syncthreads();
    double r = 0;
#pragma unroll
    for (int i = 0; i < 16; ++i) r += sc[i];
    __syncthreads();
    return r;
}

// ---- FUSED: canonicalize tokens (int32 OR int64) + per-token LN stats ----
__global__ __launch_bounds__(256) void k_tok_stats(const int* __restrict__ tok32,
                                                   signed char* __restrict__ tokc,
                                                   double* __restrict__ mu, double* __restrict__ rs) {
    __shared__ int flag;
    __shared__ double sc[4];
    int T = blockIdx.x, tid = threadIdx.x;
    if (tid == 0) {
        int nz = 0;
        for (int i = 1; i < 512; i += 2) nz |= tok32[i];
        flag = nz;
    }
    __syncthreads();
    bool is64 = (flag == 0);
    signed char* row = tokc + (size_t)T * DIM;
    double s = 0;
#pragma unroll
    for (int it = 0; it < 4; ++it) {
        size_t idx = (size_t)T * 1024 + it * BD + tid;
        int v = is64 ? tok32[2 * idx] : tok32[idx];
        row[it * BD + tid] = (signed char)v;
        s += (double)v;
    }
    s = block_sum(s, sc);
    double m = s * (1.0 / 1024.0);
    double ss = 0;
    __syncthreads();
    for (int i = tid; i < DIM; i += BD) { double d = (double)row[i] - m; ss += d * d; }
    ss = block_sum(ss, sc);
    if (tid == 0) { mu[T] = m; rs[T] = 1.0 / sqrt(ss * (1.0 / 1024.0) + 1e-5); }
}

// ---- init: xl (fp32; holds only 0/1 -> exact) = last token row; LN stats ----
__global__ __launch_bounds__(256) void k_init(const signed char* __restrict__ tokc,
                                              const double* __restrict__ mu, const double* __restrict__ rs,
                                              float* __restrict__ xl,
                                              double* __restrict__ mub, double* __restrict__ rsb) {
    int b = blockIdx.x, tid = threadIdx.x;
    int T = b * 256 + 255;
    if (tid == 0) { mub[b] = mu[T]; rsb[b] = rs[T]; }
    for (int i = tid; i < DIM; i += BD)
        xl[b * DIM + i] = (float)tokc[(size_t)T * DIM + i];
}

// ---- prefix K,V GEMM in fp32 -> fp32 KV cache (64-row T-tiles) ----
__global__ __launch_bounds__(256) void k_prefix(const signed char* __restrict__ tokc,
        const double* __restrict__ mu, const double* __restrict__ rs,
        const float* __restrict__ Wqkv, const float* __restrict__ bqkv,
        const float* __restrict__ g1, const float* __restrict__ b1,
        float* __restrict__ Kcf, float* __restrict__ Vcf) {
    __shared__ float Hs[64 * 65];
    __shared__ float Ws[64 * 64];
    int tid = threadIdx.x;
    int tx = tid & 63, ty = tid >> 6;
    int j0 = blockIdx.x * 64;
    int T0 = blockIdx.y * 64;
    float acc[16];
#pragma unroll
    for (int a = 0; a < 16; ++a) acc[a] = 0.f;
    for (int kc = 0; kc < DIM; kc += 64) {
#pragma unroll
        for (int it = 0; it < 4; ++it) {
            int e = tid * 4 + it * 1024;
            int k4 = e & 63, t = e >> 6;
            int T = T0 + t;
            char4  xc = *(const char4*)&tokc[(size_t)T * DIM + kc + k4];
            float4 gv = *(const float4*)&g1[kc + k4];
            float4 bv = *(const float4*)&b1[kc + k4];
            double muT = mu[T], rsT = rs[T];
            Hs[(k4 + 0) * 65 + t] = (float)(((double)xc.x - muT) * rsT * (double)gv.x + (double)bv.x);
            Hs[(k4 + 1) * 65 + t] = (float)(((double)xc.y - muT) * rsT * (double)gv.y + (double)bv.y);
            Hs[(k4 + 2) * 65 + t] = (float)(((double)xc.z - muT) * rsT * (double)gv.z + (double)bv.z);
            Hs[(k4 + 3) * 65 + t] = (float)(((double)xc.w - muT) * rsT * (double)gv.w + (double)bv.w);
        }
#pragma unroll
        for (int it = 0; it < 4; ++it) {
            int e = tid * 4 + it * 1024;
            int k = e >> 6, j = e & 63;
            float4 wv = *(const float4*)&Wqkv[(size_t)(kc + k) * 3072 + 1024 + j0 + j];
            *(float4*)&Ws[k * 64 + j] = wv;
        }
        __syncthreads();
#pragma unroll 4
        for (int k = 0; k < 64; ++k) {
            float w = Ws[k * 64 + tx];
#pragma unroll
            for (int a = 0; a < 16; ++a)
                acc[a] += Hs[k * 65 + ty * 16 + a] * w;
        }
        __syncthreads();
    }
    int colg = j0 + tx;
    float bias = bqkv[1024 + colg];
    bool isK = (colg < 1024);
#pragma unroll
    for (int a = 0; a < 16; ++a) {
        int T = T0 + ty * 16 + a;
        int b = T >> 8, pos = T & 255;
        float v = acc[a] + bias;
        if (isK) Kcf[((size_t)b * SMAX + pos) * DIM + colg] = v;
        else     Vcf[((size_t)b * SMAX + pos) * DIM + colg - 1024] = v;
    }
}

// ---- QKV GEMV with analytic-LN staging; float4 staging loads ----
__global__ __launch_bounds__(256) void k_qkv(const float* __restrict__ xl,
        const double* __restrict__ mub, const double* __restrict__ rsb,
        const float* __restrict__ g1, const float* __restrict__ b1,
        const float* __restrict__ Wqkv, float* __restrict__ P1) {
    __shared__ double As[16 * 64];
    __shared__ float  Ws[64 * 64];
    int tid = threadIdx.x, tx = tid & 63, ty = tid >> 6;
    int j0 = blockIdx.x * 64;
    int k0 = blockIdx.y * 128;
    double acc[4] = {0, 0, 0, 0};
    for (int kc = 0; kc < 128; kc += 64) {
        {
            int bq = tid >> 4, kq = (tid & 15) * 4;
            int kk = k0 + kc + kq;
            float4 xv = *(const float4*)&xl[(size_t)bq * DIM + kk];
            float4 gv = *(const float4*)&g1[kk];
            float4 bv = *(const float4*)&b1[kk];
            double mb = mub[bq], rb = rsb[bq];
            double* d = &As[bq * 64 + kq];
            d[0] = ((double)xv.x - mb) * rb * (double)gv.x + (double)bv.x;
            d[1] = ((double)xv.y - mb) * rb * (double)gv.y + (double)bv.y;
            d[2] = ((double)xv.z - mb) * rb * (double)gv.z + (double)bv.z;
            d[3] = ((double)xv.w - mb) * rb * (double)gv.w + (double)bv.w;
        }
#pragma unroll
        for (int it = 0; it < 4; ++it) {
            int e = tid * 4 + it * 1024;
            int k = e >> 6, j = e & 63;
            float4 wv = *(const float4*)&Wqkv[(size_t)(k0 + kc + k) * 3072 + j0 + j];
            *(float4*)&Ws[k * 64 + j] = wv;
        }
        __syncthreads();
#pragma unroll 8
        for (int k = 0; k < 64; ++k) {
            double w = (double)Ws[k * 64 + tx];
            acc[0] += As[(ty * 4 + 0) * 64 + k] * w;
            acc[1] += As[(ty * 4 + 1) * 64 + k] * w;
            acc[2] += As[(ty * 4 + 2) * 64 + k] * w;
            acc[3] += As[(ty * 4 + 3) * 64 + k] * w;
        }
        __syncthreads();
    }
#pragma unroll
    for (int a = 0; a < 4; ++a)
        P1[((size_t)(blockIdx.y * 16 + ty * 4 + a)) * 3072 + j0 + tx] = (float)acc[a];
}

// ---- batched 16-row GEMV: fp32 A, fp32 partial out; float4 staging ----
__global__ __launch_bounds__(256) void mm16ff(const float* __restrict__ A, int K,
        const float* __restrict__ W, int ldw, float* __restrict__ P, int ncols) {
    __shared__ double As[16 * 64];
    __shared__ float  Ws[64 * 64];
    int tid = threadIdx.x, tx = tid & 63, ty = tid >> 6;
    int j0 = blockIdx.x * 64;
    int klen = K / gridDim.y;
    int k0 = blockIdx.y * klen;
    double acc[4] = {0, 0, 0, 0};
    for (int kc = 0; kc < klen; kc += 64) {
        {
            int bq = tid >> 4, kq = (tid & 15) * 4;
            float4 av = *(const float4*)&A[(size_t)bq * K + k0 + kc + kq];
            double* d = &As[bq * 64 + kq];
            d[0] = (double)av.x; d[1] = (double)av.y;
            d[2] = (double)av.z; d[3] = (double)av.w;
        }
#pragma unroll
        for (int it = 0; it < 4; ++it) {
            int e = tid * 4 + it * 1024;
            int k = e >> 6, j = e & 63;
            float4 wv = *(const float4*)&W[(size_t)(k0 + kc + k) * ldw + j0 + j];
            *(float4*)&Ws[k * 64 + j] = wv;
        }
        __syncthreads();
#pragma unroll 8
        for (int k = 0; k < 64; ++k) {
            double w = (double)Ws[k * 64 + tx];
            acc[0] += As[(ty * 4 + 0) * 64 + k] * w;
            acc[1] += As[(ty * 4 + 1) * 64 + k] * w;
            acc[2] += As[(ty * 4 + 2) * 64 + k] * w;
            acc[3] += As[(ty * 4 + 3) * 64 + k] * w;
        }
        __syncthreads();
    }
#pragma unroll
    for (int a = 0; a < 4; ++a)
        P[((size_t)(blockIdx.y * 16 + ty * 4 + a)) * ncols + j0 + tx] = (float)acc[a];
}

// ---- transposed-W variant: fp32 A, fp32 partial out; float4 staging ----
__global__ __launch_bounds__(256) void mm16_tf(const float* __restrict__ A, int K,
        const float* __restrict__ Wt, float* __restrict__ P, int ncols) {
    __shared__ double As[16 * 64];
    __shared__ float  Ws[64 * 65];
    int tid = threadIdx.x, tx = tid & 63, ty = tid >> 6;
    int j0 = blockIdx.x * 64;
    int klen = K / gridDim.y;
    int k0 = blockIdx.y * klen;
    double acc[4] = {0, 0, 0, 0};
    for (int kc = 0; kc < klen; kc += 64) {
        {
            int bq = tid >> 4, kq = (tid & 15) * 4;
            float4 av = *(const float4*)&A[(size_t)bq * K + k0 + kc + kq];
            double* d = &As[bq * 64 + kq];
            d[0] = (double)av.x; d[1] = (double)av.y;
            d[2] = (double)av.z; d[3] = (double)av.w;
        }
#pragma unroll
        for (int it = 0; it < 4; ++it) {
            int e = tid * 4 + it * 1024;
            int j = e >> 6, k = e & 63;
            float4 wv = *(const float4*)&Wt[(size_t)(j0 + j) * K + k0 + kc + k];
            Ws[(k + 0) * 65 + j] = wv.x;
            Ws[(k + 1) * 65 + j] = wv.y;
            Ws[(k + 2) * 65 + j] = wv.z;
            Ws[(k + 3) * 65 + j] = wv.w;
        }
        __syncthreads();
#pragma unroll 8
        for (int k = 0; k < 64; ++k) {
            double w = (double)Ws[k * 65 + tx];
            acc[0] += As[(ty * 4 + 0) * 64 + k] * w;
            acc[1] += As[(ty * 4 + 1) * 64 + k] * w;
            acc[2] += As[(ty * 4 + 2) * 64 + k] * w;
            acc[3] += As[(ty * 4 + 3) * 64 + k] * w;
        }
        __syncthreads();
    }
#pragma unroll
    for (int a = 0; a < 4; ++a)
        P[((size_t)(blockIdx.y * 16 + ty * 4 + a)) * ncols + j0 + tx] = (float)acc[a];
}

// ---- FUSED: combine(P1) + scores + fresh K/V append. grid (NB, 9) ----
// Combine staging vectorized: 1 float4/thread covers all 1024 cols.
// Per-element sum order unchanged -> bitwise-identical q/K/V/scores.
__global__ __launch_bounds__(256) void k_scores(const float* __restrict__ P1,
        const float* __restrict__ bqkv, float* __restrict__ Kcf, float* __restrict__ Vcf,
        double* __restrict__ sco, int S) {
    __shared__ double qs[DIM];
    __shared__ float  ksf[DIM];
    int b = blockIdx.x, tid = threadIdx.x;
    int pos = S - 1;
    {
        int c4 = tid * 4;
        float4 bq4 = *(const float4*)&bqkv[c4];
        double s0 = bq4.x, s1 = bq4.y, s2 = bq4.z, s3 = bq4.w;
#pragma unroll
        for (int ks = 0; ks < 8; ++ks) {
            float4 pv = *(const float4*)&P1[((size_t)(ks * 16 + b)) * 3072 + c4];
            s0 += (double)pv.x; s1 += (double)pv.y; s2 += (double)pv.z; s3 += (double)pv.w;
        }
        qs[c4] = s0; qs[c4 + 1] = s1; qs[c4 + 2] = s2; qs[c4 + 3] = s3;
    }
    if ((int)blockIdx.y == (pos >> 5)) {
        int c4 = tid * 4;
        float4 bk4 = *(const float4*)&bqkv[1024 + c4];
        float4 bv4 = *(const float4*)&bqkv[2048 + c4];
        double k0s = bk4.x, k1s = bk4.y, k2s = bk4.z, k3s = bk4.w;
        double v0s = bv4.x, v1s = bv4.y, v2s = bv4.z, v3s = bv4.w;
#pragma unroll
        for (int ks = 0; ks < 8; ++ks) {
            const float* Pr = &P1[((size_t)(ks * 16 + b)) * 3072];
            float4 pk = *(const float4*)&Pr[1024 + c4];
            float4 pv = *(const float4*)&Pr[2048 + c4];
            k0s += (double)pk.x; k1s += (double)pk.y; k2s += (double)pk.z; k3s += (double)pk.w;
            v0s += (double)pv.x; v1s += (double)pv.y; v2s += (double)pv.z; v3s += (double)pv.w;
        }
        float4 kf4 = make_float4((float)k0s, (float)k1s, (float)k2s, (float)k3s);
        *(float4*)&ksf[c4] = kf4;
        *(float4*)&Kcf[((size_t)b * SMAX + pos) * DIM + c4] = kf4;
        *(float4*)&Vcf[((size_t)b * SMAX + pos) * DIM + c4] =
            make_float4((float)v0s, (float)v1s, (float)v2s, (float)v3s);
    }
    __syncthreads();
    int lane = tid & 63, w = tid >> 6;
    int base = blockIdx.y * 32 + w * 8;
    for (int r = 0; r < 8; ++r) {
        int p = base + r;
        if (p >= S) break;
        double acc = 0;
        const float4* kp4 = (p == pos) ? (const float4*)ksf
                                       : (const float4*)(Kcf + ((size_t)b * SMAX + p) * DIM);
#pragma unroll
        for (int ii = 0; ii < 4; ++ii) {
            float4 kv = kp4[lane + 64 * ii];
            int e = 4 * (lane + 64 * ii);
            acc += qs[e] * (double)kv.x + qs[e + 1] * (double)kv.y
                 + qs[e + 2] * (double)kv.z + qs[e + 3] * (double)kv.w;
        }
        acc = wred_sum(acc);
        if (lane == 0) sco[b * SMAX + p] = acc * 0.03125;  // /sqrt(1024)
    }
}

// ---- softmax (redundant/block) + partial PV over fp32 V -> AOp fp32 ----
__global__ __launch_bounds__(256) void k_attnp(const double* __restrict__ sco, const float* __restrict__ Vcf,
                                               float* __restrict__ AOp, int S) {
    __shared__ double ps[SMAX];
    __shared__ double sc[4];
    int b = blockIdx.x, sub = blockIdx.y, tid = threadIdx.x;
    int dch = sub & 3, sch = sub >> 2;
    double lm = -1e300;
    for (int i = tid; i < S; i += BD) { double v = sco[b * SMAX + i]; ps[i] = v; if (v > lm) lm = v; }
    __syncthreads();
    double mx = block_max(lm, sc);
    double le = 0;
    for (int i = tid; i < S; i += BD) { double e = exp(ps[i] - mx); ps[i] = e; le += e; }
    double den = block_sum(le, sc);
    int d = dch * 256 + tid;
    int p0 = sch * 36, p1 = p0 + 36; if (p1 > S) p1 = S;
    const float* Vb = Vcf + (size_t)b * SMAX * DIM + d;
    double a0 = 0, a1 = 0, a2 = 0, a3 = 0;
    int p = p0;
    for (; p + 4 <= p1; p += 4) {
        a0 += ps[p + 0] * (double)Vb[(size_t)(p + 0) * DIM];
        a1 += ps[p + 1] * (double)Vb[(size_t)(p + 1) * DIM];
        a2 += ps[p + 2] * (double)Vb[(size_t)(p + 2) * DIM];
        a3 += ps[p + 3] * (double)Vb[(size_t)(p + 3) * DIM];
    }
    for (; p < p1; ++p) a0 += ps[p] * (double)Vb[(size_t)p * DIM];
    AOp[((size_t)(sch * 16 + b)) * DIM + d] = (float)(((a0 + a1) + (a2 + a3)) / den);
}

// ---- attn-proj GEMV: float4-staged sum of 8 AOp partials, GEMV Wap -> P2 ----
__global__ __launch_bounds__(256) void k_aproj(const float* __restrict__ AOp,
        const float* __restrict__ Wap, float* __restrict__ P2) {
    __shared__ double As[16 * 64];
    __shared__ float  Ws[64 * 64];
    int tid = threadIdx.x, tx = tid & 63, ty = tid >> 6;
    int j0 = blockIdx.x * 64;
    int k0 = blockIdx.y * 128;
    double acc[4] = {0, 0, 0, 0};
    for (int kc = 0; kc < 128; kc += 64) {
        {
            int bq = tid >> 4, kq = (tid & 15) * 4;
            const float* col = AOp + (size_t)bq * DIM + k0 + kc + kq;
            double s0 = 0, s1 = 0, s2 = 0, s3 = 0;
#pragma unroll
            for (int sct = 0; sct < 8; ++sct) {
                float4 v = *(const float4*)&col[(size_t)sct * 16 * DIM];
                s0 += (double)v.x; s1 += (double)v.y; s2 += (double)v.z; s3 += (double)v.w;
            }
            double* d = &As[bq * 64 + kq];
            d[0] = s0; d[1] = s1; d[2] = s2; d[3] = s3;
        }
#pragma unroll
        for (int it = 0; it < 4; ++it) {
            int e = tid * 4 + it * 1024;
            int k = e >> 6, j = e & 63;
            float4 wv = *(const float4*)&Wap[(size_t)(k0 + kc + k) * DIM + j0 + j];
            *(float4*)&Ws[k * 64 + j] = wv;
        }
        __syncthreads();
#pragma unroll 8
        for (int k = 0; k < 64; ++k) {
            double w = (double)Ws[k * 64 + tx];
            acc[0] += As[(ty * 4 + 0) * 64 + k] * w;
            acc[1] += As[(ty * 4 + 1) * 64 + k] * w;
            acc[2] += As[(ty * 4 + 2) * 64 + k] * w;
            acc[3] += As[(ty * 4 + 3) * 64 + k] * w;
        }
        __syncthreads();
    }
#pragma unroll
    for (int a = 0; a < 4; ++a)
        P2[((size_t)(blockIdx.y * 16 + ty * 4 + a)) * DIM + j0 + tx] = (float)acc[a];
}

// ---- x2 = xl + aproj + bias; LN2 -> h2. 1024 threads, 1 elem/thread ----
__global__ __launch_bounds__(1024) void k_ln2(const float* __restrict__ xl, const float* __restrict__ P2,
        const float* __restrict__ bap, const float* __restrict__ g2, const float* __restrict__ b2,
        float* __restrict__ x2, float* __restrict__ h2) {
    __shared__ double sc[16];
    int b = blockIdx.x, i = threadIdx.x;
    double s0 = (double)xl[b * DIM + i] + (double)bap[i];
#pragma unroll
    for (int ks = 0; ks < 8; ++ks) s0 += (double)P2[((size_t)(ks * 16 + b)) * DIM + i];
    x2[b * DIM + i] = (float)s0;
    double s = block_sum16(s0, sc);
    double m = s * (1.0 / 1024.0);
    double d = s0 - m;
    double ss = block_sum16(d * d, sc);
    double r = 1.0 / sqrt(ss * (1.0 / 1024.0) + 1e-5);
    h2[b * DIM + i] = (float)(d * r * (double)g2[i] + (double)b2[i]);
}

// ---- m = gelu_new(fc + bias): fp32 P3 in, fp32 m out, fp64 math ----
__global__ __launch_bounds__(256) void k_gelu(const float* __restrict__ P3, const float* __restrict__ bfc,
                                              float* __restrict__ m) {
    int b = blockIdx.x;
    int i = blockIdx.y * BD + threadIdx.x;
    double u = (double)bfc[i];
    for (int ks = 0; ks < 8; ++ks) u += (double)P3[((size_t)(ks * 16 + b)) * 4096 + i];
    double c = sqrt(2.0 / M_PI);
    double inner = c * (u + 0.044715 * u * u * u);
    m[(size_t)b * 4096 + i] = (float)(0.5 * u * (1.0 + tanh(inner)));
}

// ---- x3 = x2 + mproj + bias; LNf -> hf. 1024 threads, 1 elem/thread ----
__global__ __launch_bounds__(1024) void k_lnf(const float* __restrict__ x2, const float* __restrict__ P4,
        const float* __restrict__ bmp, const float* __restrict__ gf, const float* __restrict__ bf,
        float* __restrict__ hf) {
    __shared__ double sc[16];
    int b = blockIdx.x, i = threadIdx.x;
    double s0 = (double)x2[b * DIM + i] + (double)bmp[i];
#pragma unroll
    for (int ks = 0; ks < 16; ++ks) s0 += (double)P4[((size_t)(ks * 16 + b)) * DIM + i];
    double s = block_sum16(s0, sc);
    double m = s * (1.0 / 1024.0);
    double d = s0 - m;
    double ss = block_sum16(d * d, sc);
    double r = 1.0 / sqrt(ss * (1.0 / 1024.0) + 1e-5);
    hf[b * DIM + i] = (float)(d * r * (double)gf[i] + (double)bf[i]);
}

// ---- logits + threshold -> xl; analytic LN1 stats. 1024 threads ----
__global__ __launch_bounds__(1024) void k_final(const float* __restrict__ P5, float* __restrict__ out,
                                                float* __restrict__ xl,
                                                double* __restrict__ mub, double* __restrict__ rsb, int t) {
    __shared__ double sc[16];
    int b = blockIdx.x, tid = threadIdx.x;
    double cnt = 0;
    if (tid < NPROPS) {
        double lg = 0;
#pragma unroll
        for (int ks = 0; ks < 8; ++ks) lg += (double)P5[((size_t)(ks * 16 + b)) * NPROPS + tid];
        out[((size_t)b * NSTEPS + t) * NPROPS + tid] = (float)lg;
        float bit = (lg > 0.0) ? 1.0f : 0.0f;
        xl[b * DIM + tid] = 0.0f;
        xl[b * DIM + NPROPS + tid] = bit;
        cnt = (double)bit;
    }
    double s = block_sum16(cnt, sc);
    double mean = s * (1.0 / 1024.0);
    double var = mean - mean * mean;
    double r = 1.0 / sqrt(var + 1e-5);
    if (tid == 0) { mub[b] = mean; rsb[b] = r; }
}

extern "C" void kernel_launch(void* const* d_in, const int* in_sizes, int n_in,
                              void* d_out, int out_size, void* d_ws, size_t ws_size,
                              hipStream_t stream) {
    const int*   tok  = (const int*)d_in[0];
    const float* Wqkv = (const float*)d_in[1];
    const float* bqkv = (const float*)d_in[2];
    const float* Wap  = (const float*)d_in[3];
    const float* bap  = (const float*)d_in[4];
    const float* g1   = (const float*)d_in[5];
    const float* b1   = (const float*)d_in[6];
    const float* g2   = (const float*)d_in[7];
    const float* b2   = (const float*)d_in[8];
    const float* Wfc  = (const float*)d_in[9];
    const float* bfc  = (const float*)d_in[10];
    const float* Wmp  = (const float*)d_in[11];
    const float* bmp  = (const float*)d_in[12];
    const float* gf   = (const float*)d_in[13];
    const float* bf   = (const float*)d_in[14];
    const float* Wsc  = (const float*)d_in[15];
    float* out = (float*)d_out;

    char* w = (char*)d_ws;
    size_t off = 0;
    auto alloc = [&](size_t bytes) -> void* {
        void* p = (void*)(w + off);
        off += (bytes + 255) & ~(size_t)255;
        return p;
    };
    float*       Kcf  = (float*)alloc((size_t)NB * SMAX * DIM * 4);
    float*       Vcf  = (float*)alloc((size_t)NB * SMAX * DIM * 4);
    double*      mu   = (double*)alloc(4096 * 8);
    double*      rs   = (double*)alloc(4096 * 8);
    double*      mub  = (double*)alloc(NB * 8);
    double*      rsb  = (double*)alloc(NB * 8);
    float*       xl   = (float*)alloc((size_t)NB * DIM * 4);
    double*      sco  = (double*)alloc((size_t)NB * SMAX * 8);
    float*       AOp  = (float*)alloc((size_t)8 * NB * DIM * 4);
    float*       x2   = (float*)alloc((size_t)NB * DIM * 4);
    float*       h2   = (float*)alloc((size_t)NB * DIM * 4);
    float*       m_   = (float*)alloc((size_t)NB * 4096 * 4);
    float*       hf   = (float*)alloc((size_t)NB * DIM * 4);
    float*       P1   = (float*)alloc((size_t)8 * NB * 3072 * 4);
    float*       P2   = (float*)alloc((size_t)8 * NB * 1024 * 4);
    float*       P3   = (float*)alloc((size_t)8 * NB * 4096 * 4);
    float*       P4   = (float*)alloc((size_t)16 * NB * 1024 * 4);
    float*       P5   = (float*)alloc((size_t)8 * NB * 512 * 4);
    signed char* tokc = (signed char*)alloc((size_t)NTOK);
    if (off > ws_size) return;  // fail visibly (output stays poisoned)

    k_tok_stats<<<4096, BD, 0, stream>>>(tok, tokc, mu, rs);
    k_init<<<NB, BD, 0, stream>>>(tokc, mu, rs, xl, mub, rsb);
    k_prefix<<<dim3(32, 64), BD, 0, stream>>>(tokc, mu, rs, Wqkv, bqkv, g1, b1, Kcf, Vcf);

    for (int t = 0; t < NSTEPS; ++t) {
        int S = 256 + t;
        k_qkv<<<dim3(48, 8), BD, 0, stream>>>(xl, mub, rsb, g1, b1, Wqkv, P1);
        k_scores<<<dim3(NB, 9), BD, 0, stream>>>(P1, bqkv, Kcf, Vcf, sco, S);
        k_attnp<<<dim3(NB, 32), BD, 0, stream>>>(sco, Vcf, AOp, S);
        k_aproj<<<dim3(16, 8), BD, 0, stream>>>(AOp, Wap, P2);
        k_ln2<<<NB, 1024, 0, stream>>>(xl, P2, bap, g2, b2, x2, h2);
        mm16ff<<<dim3(64, 8), BD, 0, stream>>>(h2, 1024, Wfc, 4096, P3, 4096);
        k_gelu<<<dim3(NB, 16), BD, 0, stream>>>(P3, bfc, m_);
        mm16ff<<<dim3(16, 16), BD, 0, stream>>>(m_, 4096, Wmp, 1024, P4, 1024);
        k_lnf<<<NB, 1024, 0, stream>>>(x2, P4, bmp, gf, bf, hf);
        mm16_tf<<<dim3(8, 8), BD, 0, stream>>>(hf, 1024, Wsc, P5, 512);
        k_final<<<NB, 1024, 0, stream>>>(P5, out, xl, mub, rsb, t);
    }
}